// Round 2
// baseline (531.881 us; speedup 1.0000x reference)
//
#include <hip/hip_runtime.h>

// Fused denorm + ReLU + AdaptiveAvgPool2d(56) for patch groups S=24,32,48.
// v3: no LDS, no barriers. Each output pixel averages a <=2x2 input window
// (S < 56): r0=(i*S)/56, r1=ceil((i+1)*S/56), rc in {1,2} (same for cols).
// Input maps are 2.3-9 KB -> the <=4x reuse of window corners is served by
// L1/L2; staging through LDS was pure overhead (stage + barrier + re-read).
// One block per (n,c) map: mean/std are block-uniform (scalar loads),
// output writes are a contiguous 12.25 KB range per block (coalesced f4).

#define C_CH 256
#define OUTS 56
#define NPER 32

typedef float f4 __attribute__((ext_vector_type(4)));

template<int S>
__device__ __forceinline__ void group_body(const float* __restrict__ x,
                                           const float* __restrict__ smean,
                                           const float* __restrict__ sstd,
                                           float* __restrict__ out,
                                           int local_bid, int n_base) {
    const int n_local = local_bid >> 8;   // / 256 channels
    const int c       = local_bid & 255;
    const int n_glob  = n_base + n_local;
    const float mn = smean[n_glob * C_CH + c];
    const float sd = sstd [n_glob * C_CH + c];

    const float* __restrict__ xin = x + (size_t)(n_local * C_CH + c) * (S * S);
    f4* __restrict__ out4 = (f4*)(out + (size_t)(n_glob * C_CH + c) * (OUTS * OUTS));

    constexpr int NQ = (OUTS * OUTS) / 4;         // 784 float4 per output map
    for (int q = threadIdx.x; q < NQ; q += 256) {
        const int i  = q / (OUTS / 4);            // output row (const divisor 14)
        const int j0 = (q % (OUTS / 4)) * 4;      // first output col of this float4
        const int r0 = (i * S) / OUTS;
        const int r1 = ((i + 1) * S + OUTS - 1) / OUTS;
        const int rtwo = r1 - r0 - 1;             // 0 or 1
        const float invr = rtwo ? 0.5f : 1.0f;
        const float* __restrict__ row0 = xin + r0 * S;
        const float* __restrict__ row1 = row0 + rtwo * S;   // ==row0 when rc==1

        float o[4];
        #pragma unroll
        for (int k = 0; k < 4; ++k) {
            const int j  = j0 + k;
            const int c0 = (j * S) / OUTS;
            const int c1 = ((j + 1) * S + OUTS - 1) / OUTS;
            const int ctwo = c1 - c0 - 1;         // 0 or 1
            // Unconditional clamped loads (duplicates hit L1; no exec-mask
            // divergence), then select-gated adds.
            float a00 = row0[c0];
            float a01 = row0[c0 + ctwo];
            float a10 = row1[c0];
            float a11 = row1[c0 + ctwo];
            a00 = fmaxf(fmaf(a00, sd, mn), 0.0f);
            a01 = fmaxf(fmaf(a01, sd, mn), 0.0f);
            a10 = fmaxf(fmaf(a10, sd, mn), 0.0f);
            a11 = fmaxf(fmaf(a11, sd, mn), 0.0f);
            float acc = a00;
            if (ctwo) acc += a01;                 // cndmask-gated adds
            if (rtwo) {
                acc += a10;
                if (ctwo) acc += a11;
            }
            const float invc = ctwo ? 0.5f : 1.0f;
            o[k] = acc * (invr * invc);           // exact: powers of 2
        }
        f4 v; v.x = o[0]; v.y = o[1]; v.z = o[2]; v.w = o[3];
        out4[q] = v;
    }
}

__global__ __launch_bounds__(256) void PPIN_DC_20753281974843_kernel(
        const float* __restrict__ p24, const float* __restrict__ p32,
        const float* __restrict__ p48, const float* __restrict__ smean,
        const float* __restrict__ sstd, float* __restrict__ out) {
    const int bid   = blockIdx.x;
    const int group = bid >> 13;      // 8192 blocks per group (32 patches * 256 ch)
    const int local = bid & 8191;
    if (group == 0)      group_body<24>(p24, smean, sstd, out, local, 0);
    else if (group == 1) group_body<32>(p32, smean, sstd, out, local, NPER);
    else                 group_body<48>(p48, smean, sstd, out, local, 2 * NPER);
}

extern "C" void kernel_launch(void* const* d_in, const int* in_sizes, int n_in,
                              void* d_out, int out_size, void* d_ws, size_t ws_size,
                              hipStream_t stream) {
    const float* p24   = (const float*)d_in[0];
    const float* p32   = (const float*)d_in[1];
    const float* p48   = (const float*)d_in[2];
    const float* smean = (const float*)d_in[3];
    const float* sstd  = (const float*)d_in[4];
    float* out = (float*)d_out;

    // 3 groups * 32 patches * 256 channels = 24576 blocks, one (n,c) map each.
    PPIN_DC_20753281974843_kernel<<<dim3(24576), dim3(256), 0, stream>>>(
        p24, p32, p48, smean, sstd, out);
}

// Round 3
// 390.790 us; speedup vs baseline: 1.3610x; 1.3610x over previous
//
#include <hip/hip_runtime.h>

// Fused denorm + ReLU + AdaptiveAvgPool2d(56) for patch groups S=24,32,48.
// v4 = v0 structure (LDS-staged, one (n,c) map per block) + branch-free
// compute phase:
//   - unconditional paired LDS reads (c0, c0+1) x rows (r0, r0+rtwo)
//     -> compiler merges to ds_read2_b32 (2 instrs/pixel vs 4 gated reads)
//   - float-gated accumulation (fmaf with 0/1 gates), no exec-mask branches
//   - scale 1/(rc*cc) via selects of {1.0, 0.5} (exact powers of 2)
//   - lds[S*S] zeroed so the unconditional +1 read never sees garbage/NaN
// Windows are <=2x2 since S < 56: r0=(i*S)/56, r1=ceil((i+1)*S/56).

#define C_CH 256
#define OUTS 56
#define NPER 32

typedef float f4 __attribute__((ext_vector_type(4)));

template<int S>
__device__ __forceinline__ void group_body(const float* __restrict__ x,
                                           const float* __restrict__ smean,
                                           const float* __restrict__ sstd,
                                           float* __restrict__ out,
                                           int local_bid, int n_base,
                                           float* __restrict__ lds) {
    const int n_local = local_bid >> 8;   // / 256 channels
    const int c       = local_bid & 255;
    const int n_glob  = n_base + n_local;
    const float mn = smean[n_glob * C_CH + c];
    const float sd = sstd [n_glob * C_CH + c];

    const float* __restrict__ xin = x + (size_t)(n_local * C_CH + c) * (S * S);
    const int tid = threadIdx.x;

    // Stage t = relu(x*sd + mn) into LDS with coalesced f4 loads.
    constexpr int NV = (S * S) / 4;       // divisible by 4 for all S here
    const f4* __restrict__ x4 = (const f4*)xin;
    f4* __restrict__ l4 = (f4*)lds;
    for (int idx = tid; idx < NV; idx += 256) {
        f4 v = x4[idx];
        v.x = fmaxf(fmaf(v.x, sd, mn), 0.0f);
        v.y = fmaxf(fmaf(v.y, sd, mn), 0.0f);
        v.z = fmaxf(fmaf(v.z, sd, mn), 0.0f);
        v.w = fmaxf(fmaf(v.w, sd, mn), 0.0f);
        l4[idx] = v;
    }
    if (tid == 0) lds[S * S] = 0.0f;      // guard slot for unconditional +1 reads
    __syncthreads();

    f4* __restrict__ out4 = (f4*)(out + (size_t)(n_glob * C_CH + c) * (OUTS * OUTS));

    constexpr int NQ = (OUTS * OUTS) / 4; // 784 float4 per output map
    for (int q = tid; q < NQ; q += 256) {
        const int i  = q / (OUTS / 4);            // output row (const divisor 14)
        const int j0 = (q % (OUTS / 4)) * 4;      // first output col of this f4
        const int r0 = (i * S) / OUTS;
        const int r1 = ((i + 1) * S + OUTS - 1) / OUTS;
        const int rtwo = r1 - r0 - 1;             // 0 or 1
        const float fr   = rtwo ? 1.0f : 0.0f;    // row gate
        const float invr = rtwo ? 0.5f : 1.0f;
        const float* __restrict__ row0 = lds + r0 * S;
        const float* __restrict__ row1 = row0 + rtwo * S;   // ==row0 when rc==1

        float o[4];
        #pragma unroll
        for (int k = 0; k < 4; ++k) {
            const int j  = j0 + k;
            const int c0 = (j * S) / OUTS;
            const int c1 = ((j + 1) * S + OUTS - 1) / OUTS;
            const int ctwo = c1 - c0 - 1;         // 0 or 1
            const float fc   = ctwo ? 1.0f : 0.0f;
            const float invc = ctwo ? 0.5f : 1.0f;
            // Unconditional adjacent-pair reads -> ds_read2_b32; values past the
            // window are finite (guard slot / next-row data) and gated to 0.
            const float a00 = row0[c0];
            const float a01 = row0[c0 + 1];
            const float a10 = row1[c0];
            const float a11 = row1[c0 + 1];
            float top = fmaf(fc, a01, a00);       // a00 (+ a01 if 2-wide)
            float bot = fmaf(fc, a11, a10);
            float acc = fmaf(fr, bot, top);       // (+ bottom row if 2-tall)
            o[k] = (acc * invc) * invr;           // exact: powers of 2
        }
        f4 v; v.x = o[0]; v.y = o[1]; v.z = o[2]; v.w = o[3];
        out4[q] = v;
    }
}

__global__ __launch_bounds__(256) void PPIN_DC_20753281974843_kernel(
        const float* __restrict__ p24, const float* __restrict__ p32,
        const float* __restrict__ p48, const float* __restrict__ smean,
        const float* __restrict__ sstd, float* __restrict__ out) {
    __shared__ float lds[48 * 48 + 1];    // +1 guard slot
    const int bid   = blockIdx.x;
    const int group = bid >> 13;          // 8192 blocks per group (32*256 maps)
    const int local = bid & 8191;
    if (group == 0)      group_body<24>(p24, smean, sstd, out, local, 0,        lds);
    else if (group == 1) group_body<32>(p32, smean, sstd, out, local, NPER,     lds);
    else                 group_body<48>(p48, smean, sstd, out, local, 2 * NPER, lds);
}

extern "C" void kernel_launch(void* const* d_in, const int* in_sizes, int n_in,
                              void* d_out, int out_size, void* d_ws, size_t ws_size,
                              hipStream_t stream) {
    const float* p24   = (const float*)d_in[0];
    const float* p32   = (const float*)d_in[1];
    const float* p48   = (const float*)d_in[2];
    const float* smean = (const float*)d_in[3];
    const float* sstd  = (const float*)d_in[4];
    float* out = (float*)d_out;

    // 3 groups * 32 patches * 256 channels = 24576 blocks, one (n,c) map each.
    PPIN_DC_20753281974843_kernel<<<dim3(24576), dim3(256), 0, stream>>>(
        p24, p32, p48, smean, sstd, out);
}